// Round 14
// baseline (62.388 us; speedup 1.0000x reference)
//
#include <hip/hip_runtime.h>
#include <hip/hip_fp16.h>

namespace {

constexpr int B = 16, C = 3, H = 512, W = 1024;
constexpr int HW = H * W;               // 2^19
constexpr int SLABW = 256, SLABH = 64;
constexpr int XH  = 16;                 // x halo
constexpr int SWD = SLABW + 2 * XH;     // 288 staged cols
constexpr int PAIRS = SWD / 2;          // 144 half2 pairs per row
constexpr int PADP = 147;               // pair stride; row bank-shift 19, gcd(19,32)=1
constexpr int RING = 32;                // ring rows (power of 2)
constexpr int RA = 13;                  // rows behind  (3.25 sigma)
constexpr int RB = 14;                  // rows ahead   (3.5+ sigma)
constexpr int RPS = 4;                  // rows per step
constexpr int BLOCK = 1024;
constexpr int TX = W / SLABW;           // 4
constexpr int TY = H / SLABH;           // 8
constexpr int GRID = B * TX * TY;       // 512 blocks = 2/CU (32 waves = HW cap)
constexpr int PF_ROWS = RA + RB + 1;    // 28 prefill rows
constexpr int STG_P = C * RPS * PAIRS;  // 1728 staged pairs / step
constexpr int CHS = RING * PADP;        // 4704 dwords (18816 B/channel)

constexpr float INV_W = 1.0f / 1024.0f;
constexpr float INV_H = 1.0f / 512.0f;

typedef __fp16 h2v __attribute__((ext_vector_type(2)));

// 4B-aligned float2 (adjacent-corner pair at arbitrary dword offset)
__device__ __forceinline__ float2 ld2g(const float* p) {
    struct __attribute__((packed, aligned(4))) F2 { float a, b; };
    const F2 v = *reinterpret_cast<const F2*>(p);
    return make_float2(v.a, v.b);
}

// RNE pack of two f32 into packed half2 dword
__device__ __forceinline__ uint32_t packh2(float a, float b) {
    return (uint32_t)__half_as_ushort(__float2half_rn(a))
         | ((uint32_t)__half_as_ushort(__float2half_rn(b)) << 16);
}
// (hi:lo) >> sh, sh in {0,16} -> v_alignbit_b32
__device__ __forceinline__ uint32_t alignsel(uint32_t hi, uint32_t lo, int sh) {
    return (uint32_t)(((((uint64_t)hi) << 32) | (uint64_t)lo) >> sh);
}
__device__ __forceinline__ __half2 ash2(uint32_t hi, uint32_t lo, int sh) {
    return __builtin_bit_cast(__half2, alignsel(hi, lo, sh));
}

__global__ __launch_bounds__(BLOCK, 8) void flow_loss_partial(
    const float* __restrict__ flow,   // (B,H,W,2)
    const float* __restrict__ im1,    // (B,C,H,W)
    const float* __restrict__ im2,    // (B,C,H,W)
    float* __restrict__ partials)     // [GRID]
{
    __shared__ uint32_t sm32[C * CHS];        // 56448 B -> 2 blocks/CU
    __shared__ float red[BLOCK / 64];

    const int tid = threadIdx.x;
    const int bid = blockIdx.x;
    const int b   = bid >> 5;                 // 32 slabs per image
    const int tt  = bid & 31;
    const int tyi = tt >> 2;                  // 8 y-slabs
    const int txi = tt & 3;                   // 4 x-slabs
    const int xbase  = txi * SLABW;
    const int yStart = tyi * SLABH;
    const int xb0    = xbase - XH;            // even

    const float* __restrict__ im1b = im1 + b * C * HW;
    const float* __restrict__ im2b = im2 + b * C * HW;
    const float* __restrict__ flb  = flow + 2 * (b * HW);

    // ---------------- prefill ring: rows yStart-RA .. yStart+RB ----------------
    for (int e = tid; e < PF_ROWS * C * PAIRS; e += BLOCK) {
        const int q  = e % PAIRS;
        const int rc = e / PAIRS;             // 0..83
        const int c  = rc / PF_ROWS;
        const int ri = rc - c * PF_ROWS;
        const int row = yStart - RA + ri;
        if (row >= 0) {                       // row <= yStart+RB < H always
            const int g0 = min(max(xb0 + 2 * q, 0), W - 1);
            const int g1 = min(max(xb0 + 2 * q + 1, 0), W - 1);
            const float a = im1b[c * HW + row * W + g0];
            const float d = im1b[c * HW + row * W + g1];
            sm32[c * CHS + (row & (RING - 1)) * PADP + q] = packh2(a, d);
        }
    }

    // ---- hoisted staging descriptors (tid-dependent only), pair granularity ----
    // k=0: e = tid always active. k=1: active iff tid < STG_P-1024 (=704).
    int  stSr[2], stG[2], stL[2];
    bool stPI[2];
    const bool stOK1 = (tid < STG_P - BLOCK);
#pragma unroll
    for (int k = 0; k < 2; ++k) {
        const int e  = (k == 0) ? tid : (stOK1 ? BLOCK + tid : 0);
        const int q  = e % PAIRS;
        const int rc = e / PAIRS;             // 0..11
        const int c  = rc >> 2;
        stSr[k] = rc & 3;
        const int p = xb0 + 2 * q;            // even pair base col
        stPI[k] = (p >= 0) & (p < W);         // interior pair (p, p+1 both valid)
        // edge pairs provably duplicate one clamped scalar (p<0 -> both 0; p>=W -> both W-1)
        stG[k] = c * HW + (stPI[k] ? p : min(max(p, 0), W - 1));
        stL[k] = c * CHS + q;
    }

    // issue staged loads for rows r0..r0+RPS-1 into regs (no LDS touch)
    auto issue = [&](int r0, int (&sIdx)[2], uint32_t (&sVal)[2]) {
#pragma unroll
        for (int k = 0; k < 2; ++k) {
            const int srow = r0 + stSr[k];
            int idx = -1; uint32_t v = 0;
            const bool act = (k == 0 || stOK1) & (srow < H);
            if (act) {
                const float* base = im1b + stG[k] + (srow << 10);
                if (stPI[k]) {
                    const float2 t = ld2g(base);
                    v = packh2(t.x, t.y);
                } else {
                    const float a = *base;
                    v = packh2(a, a);
                }
                idx = stL[k] + (srow & (RING - 1)) * PADP;
            }
            sIdx[k] = idx; sVal[k] = v;
        }
    };

    // A = staged rows committed at end of the CURRENT step (issued 1 step early)
    int sIA[2]; uint32_t sVA[2];
    issue(yStart + RB + 1, sIA, sVA);

    const int colp = tid & (SLABW - 1);
    const int prow = tid >> 8;                // 0..3
    const int x = xbase + colp;
    // exact: x has <=10 mantissa bits; pow-2 scale and -1 are exact
    const float base_x = (float)x * (2.0f * INV_W) - 1.0f;

    __syncthreads();                          // prefill visible

    float acc = 0.0f;

#pragma unroll 1
    for (int ys = yStart; ys < yStart + SLABH; ys += RPS) {
        // ---- issue NEXT step's staged im1 rows (depth-2 prefetch) ----
        int sIB[2]; uint32_t sVB[2];
        issue(ys + RB + 1 + RPS, sIB, sVB);

        // ---- compute this thread's pixel (ring reads rows ys-RA..ys+RB) ----
        const int y = ys + prow;
        const int zoff = y * W + x;
        const float2 f = *reinterpret_cast<const float2*>(flb + 2 * zoff);

        // bit-exact compressed index math (proof: round-8 note)
        const float base_y = (float)y * (2.0f * INV_H) - 1.0f;  // exact
        const float gx = __builtin_fmaf(f.x, INV_W, base_x);
        const float gy = __builtin_fmaf(f.y, INV_H, base_y);
        const float ixf = __builtin_fmaf(gx + 1.0f, 512.0f, -0.5f);
        const float iyf = __builtin_fmaf(gy + 1.0f, 256.0f, -0.5f);

        const float x0f = floorf(ixf), y0f = floorf(iyf);
        const float wx1 = ixf - x0f, wx0 = 1.0f - wx1;
        const float wy1 = iyf - y0f, wy0 = 1.0f - wy1;
        const int x0 = (int)x0f, y0 = (int)y0f;
        const int y1 = y0 + 1;
        const bool vx0 = (x0 >= 0) & (x0 < W);
        const bool vx1 = (x0 >= -1) & (x0 < W - 1);     // == valid(x1)
        const bool vy0 = (y0 >= 0) & (y0 < H);
        const bool vy1 = (y1 >= 0) & (y1 < H);
        // s0 = (x0c != xL) <=> x0 >= W-1 ; s1 = (x1c != xL) <=> x0 >= 0  (round-12 proof)
        const bool s0 = (x0 >= W - 1), s1 = (x0 >= 0);

        // weight-fold (round-13 proof, bit-exact in f32)
        const float px0 = wx0 * (float)vx0;
        const float px1 = wx1 * (float)vx1;
        const float u0 = (s0 ? 0.0f : px0) + (s1 ? 0.0f : px1);
        const float u1 = (s0 ? px0 : 0.0f) + (s1 ? px1 : 0.0f);
        const float mT = wy0 * (float)vy0;
        const float mB = wy1 * (float)vy1;
        const float aT0 = mT * u0, aT1 = mT * u1;
        const float aB0 = mB * u0, aB1 = mB * u1;

        const int xL  = min(max(x0, 0), W - 2);
        const int y0c = min(max(y0, 0), H - 1);
        const int y1c = min(max(y1, 0), H - 1);

        const int jj = xL - xbase + XH;
        const bool inR = (y0c >= ys - RA) & (y1c <= ys + RB) &
                         ((unsigned)jj <= (unsigned)(SWD - 2));

        const float z0 = im2b[zoff];
        const float z1 = im2b[HW + zoff];
        const float z2 = im2b[2 * HW + zoff];

        float wp0, wp1, wp2;
        if (inR) {
            // packed-f16 weights (rtz; error analysis in round-14 note)
            const __half2 wT = __builtin_bit_cast(__half2, __builtin_amdgcn_cvt_pkrtz(aT0, aT1));
            const __half2 wB = __builtin_bit_cast(__half2, __builtin_amdgcn_cvt_pkrtz(aB0, aB1));
            const int q  = jj >> 1;
            const int sh = (jj & 1) << 4;
            const int aT = (y0c & (RING - 1)) * PADP + q;
            const int aB = (y1c & (RING - 1)) * PADP + q;
            // per (row,channel): adjacent dword pair -> ds_read2_b32
            const uint32_t dT0a = sm32[aT],           dT0b = sm32[aT + 1];
            const uint32_t dB0a = sm32[aB],           dB0b = sm32[aB + 1];
            const uint32_t dT1a = sm32[aT + CHS],     dT1b = sm32[aT + CHS + 1];
            const uint32_t dB1a = sm32[aB + CHS],     dB1b = sm32[aB + CHS + 1];
            const uint32_t dT2a = sm32[aT + 2 * CHS], dT2b = sm32[aT + 2 * CHS + 1];
            const uint32_t dB2a = sm32[aB + 2 * CHS], dB2b = sm32[aB + 2 * CHS + 1];
            const __half2 r0 = __hfma2(ash2(dB0b, dB0a, sh), wB, __hmul2(ash2(dT0b, dT0a, sh), wT));
            const __half2 r1 = __hfma2(ash2(dB1b, dB1a, sh), wB, __hmul2(ash2(dT1b, dT1a, sh), wT));
            const __half2 r2 = __hfma2(ash2(dB2b, dB2a, sh), wB, __hmul2(ash2(dT2b, dT2a, sh), wT));
            wp0 = __low2float(r0) + __high2float(r0);
            wp1 = __low2float(r1) + __high2float(r1);
            wp2 = __low2float(r2) + __high2float(r2);
        } else {                              // rare (~0.1%/px): exact f32 global path
            const int oT = y0c * W + xL, oB = y1c * W + xL;
            const float2 ta = ld2g(im1b + oT),            ba = ld2g(im1b + oB);
            const float2 tb = ld2g(im1b + HW + oT),       bb = ld2g(im1b + HW + oB);
            const float2 tc = ld2g(im1b + 2 * HW + oT),   bc = ld2g(im1b + 2 * HW + oB);
            wp0 = ((aT0 * ta.x + aT1 * ta.y) + aB0 * ba.x) + aB1 * ba.y;
            wp1 = ((aT0 * tb.x + aT1 * tb.y) + aB0 * bb.x) + aB1 * bb.y;
            wp2 = ((aT0 * tc.x + aT1 * tc.y) + aB0 * bc.x) + aB1 * bc.y;
        }
        acc += fabsf(z0 - wp0) + fabsf(z1 - wp1) + fabsf(z2 - wp2);

        // ---- commit A: written slots (rows ys+15..ys+18 -> old ys-17..ys-14)
        // are disjoint from all rows read this step ([ys-13, ys+14]); one
        // barrier orders step->step (round-7 proof, re-derived for RA=13/RB=14). ----
#pragma unroll
        for (int k = 0; k < 2; ++k)
            if (sIA[k] >= 0) sm32[sIA[k]] = sVA[k];
        __syncthreads();

#pragma unroll
        for (int k = 0; k < 2; ++k) { sIA[k] = sIB[k]; sVA[k] = sVB[k]; }
    }

    // ---------------- block reduction ----------------
#pragma unroll
    for (int o = 32; o > 0; o >>= 1)
        acc += __shfl_down(acc, o, 64);
    const int lane = tid & 63;
    const int wid  = tid >> 6;
    if (lane == 0) red[wid] = acc;
    __syncthreads();
    if (tid == 0) {
        float s = 0.0f;
#pragma unroll
        for (int wv = 0; wv < BLOCK / 64; ++wv) s += red[wv];
        partials[bid] = s;
    }
}

__global__ __launch_bounds__(256) void flow_loss_reduce(
    const float* __restrict__ partials, float* __restrict__ out)
{
    __shared__ double lds[256];
    double acc = 0.0;
    for (int i = threadIdx.x; i < GRID; i += 256) acc += (double)partials[i];
    lds[threadIdx.x] = acc;
    __syncthreads();
    for (int o = 128; o > 0; o >>= 1) {
        if (threadIdx.x < o) lds[threadIdx.x] += lds[threadIdx.x + o];
        __syncthreads();
    }
    if (threadIdx.x == 0) out[0] = (float)(lds[0] / (double)(W * H));
}

} // namespace

extern "C" void kernel_launch(void* const* d_in, const int* in_sizes, int n_in,
                              void* d_out, int out_size, void* d_ws, size_t ws_size,
                              hipStream_t stream) {
    const float* flow = (const float*)d_in[0];
    const float* im1  = (const float*)d_in[1];
    const float* im2  = (const float*)d_in[2];
    float* out = (float*)d_out;
    float* partials = (float*)d_ws;

    flow_loss_partial<<<GRID, BLOCK, 0, stream>>>(flow, im1, im2, partials);
    flow_loss_reduce<<<1, 256, 0, stream>>>(partials, out);
}

// Round 15
// 60.498 us; speedup vs baseline: 1.0312x; 1.0312x over previous
//
#include <hip/hip_runtime.h>
#include <hip/hip_fp16.h>

namespace {

constexpr int B = 16, C = 3, H = 512, W = 1024;
constexpr int HW = H * W;               // 2^19
constexpr int SLABW = 256, SLABH = 64;
constexpr int XH  = 16;                 // x halo
constexpr int SWD = SLABW + 2 * XH;     // 288 staged cols
constexpr int PAIRS = SWD / 2;          // 144 half2 pairs per row
constexpr int QSTR  = 4;                // dwords per pair unit (c0,c1,c2,pad) -> 16B aligned
constexpr int ROWSTR = PAIRS * QSTR + 4;// 580 dwords/row (pad block keeps q=143 read in-row)
constexpr int RING = 32;                // ring rows (power of 2)
constexpr int RA = 11;                  // rows behind
constexpr int RB = 16;                  // rows ahead
constexpr int RPS = 4;                  // rows per step
constexpr int BLOCK = 1024;
constexpr int TX = W / SLABW;           // 4
constexpr int TY = H / SLABH;           // 8
constexpr int GRID = B * TX * TY;       // 512 blocks = 2/CU (32 waves = HW cap)
constexpr int PF_ROWS = RA + RB + 1;    // 28 prefill rows
constexpr int STG_U = RPS * PAIRS;      // 576 staged units / step (pair x row, all channels)

constexpr float INV_W = 1.0f / 1024.0f;
constexpr float INV_H = 1.0f / 512.0f;

// 4B-aligned float2 (adjacent-corner pair at arbitrary dword offset)
__device__ __forceinline__ float2 ld2g(const float* p) {
    struct __attribute__((packed, aligned(4))) F2 { float a, b; };
    const F2 v = *reinterpret_cast<const F2*>(p);
    return make_float2(v.a, v.b);
}

// RNE pack of two f32 into packed half2 dword
__device__ __forceinline__ uint32_t packh2(float a, float b) {
    return (uint32_t)__half_as_ushort(__float2half_rn(a))
         | ((uint32_t)__half_as_ushort(__float2half_rn(b)) << 16);
}
__device__ __forceinline__ float2 unpackh2(uint32_t u) {
    const __half2 h = __builtin_bit_cast(__half2, u);
    return make_float2(__low2float(h), __high2float(h));
}
// (hi:lo) >> sh, sh in {0,16} -> v_alignbit_b32
__device__ __forceinline__ uint32_t alignsel(uint32_t hi, uint32_t lo, int sh) {
    return (uint32_t)(((((uint64_t)hi) << 32) | (uint64_t)lo) >> sh);
}

__global__ __launch_bounds__(BLOCK, 8) void flow_loss_partial(
    const float* __restrict__ flow,   // (B,H,W,2)
    const float* __restrict__ im1,    // (B,C,H,W)
    const float* __restrict__ im2,    // (B,C,H,W)
    float* __restrict__ partials)     // [GRID]
{
    __shared__ uint32_t sm32[RING * ROWSTR];  // 74240 B -> 2 blocks/CU
    __shared__ float red[BLOCK / 64];

    const int tid = threadIdx.x;
    const int bid = blockIdx.x;
    const int b   = bid >> 5;                 // 32 slabs per image
    const int tt  = bid & 31;
    const int tyi = tt >> 2;                  // 8 y-slabs
    const int txi = tt & 3;                   // 4 x-slabs
    const int xbase  = txi * SLABW;
    const int yStart = tyi * SLABH;
    const int xb0    = xbase - XH;            // even

    const float* __restrict__ im1b = im1 + b * C * HW;
    const float* __restrict__ im2b = im2 + b * C * HW;
    const float* __restrict__ flb  = flow + 2 * (b * HW);

    // ---------------- prefill ring: rows yStart-RA .. yStart+RB ----------------
    for (int e = tid; e < PF_ROWS * PAIRS; e += BLOCK) {
        const int q  = e % PAIRS;
        const int ri = e / PAIRS;             // 0..27
        const int row = yStart - RA + ri;
        if (row >= 0) {                       // row <= yStart+RB < H always
            const int p = xb0 + 2 * q;
            const bool pi = (p >= 0) & (p <= W - 2);
            const int col = pi ? p : min(max(p, 0), W - 1);
            const float* base = im1b + row * W + col;
            uint4 v;
            if (pi) {
                const float2 c0 = ld2g(base);
                const float2 c1 = ld2g(base + HW);
                const float2 c2 = ld2g(base + 2 * HW);
                v = make_uint4(packh2(c0.x, c0.y), packh2(c1.x, c1.y), packh2(c2.x, c2.y), 0u);
            } else {                          // edge pair: both cols clamp to same col
                const float a0 = *base, a1 = base[HW], a2 = base[2 * HW];
                v = make_uint4(packh2(a0, a0), packh2(a1, a1), packh2(a2, a2), 0u);
            }
            *reinterpret_cast<uint4*>(sm32 + (row & (RING - 1)) * ROWSTR + q * QSTR) = v;
        }
    }

    // ---- hoisted staging descriptors (tid-dependent only), unit granularity ----
    const bool stAct = (tid < STG_U);
    const int  qS  = stAct ? (tid % PAIRS) : 0;
    const int  srS = stAct ? (tid / PAIRS) : 0;   // 0..3
    const int  pS  = xb0 + 2 * qS;
    const bool stPI = (pS >= 0) & (pS <= W - 2);
    const int  stCol = stPI ? pS : min(max(pS, 0), W - 1);
    const int  stLq  = qS * QSTR;

    // issue staged loads for rows r0..r0+RPS-1 into regs (no LDS touch)
    auto issue = [&](int r0, int& sIdx, uint32_t (&sVal)[3]) {
        sIdx = -1;
        const int srow = r0 + srS;
        if (stAct & (srow < H)) {
            const float* base = im1b + srow * W + stCol;
            if (stPI) {
                const float2 c0 = ld2g(base);
                const float2 c1 = ld2g(base + HW);
                const float2 c2 = ld2g(base + 2 * HW);
                sVal[0] = packh2(c0.x, c0.y);
                sVal[1] = packh2(c1.x, c1.y);
                sVal[2] = packh2(c2.x, c2.y);
            } else {
                const float a0 = *base, a1 = base[HW], a2 = base[2 * HW];
                sVal[0] = packh2(a0, a0);
                sVal[1] = packh2(a1, a1);
                sVal[2] = packh2(a2, a2);
            }
            sIdx = (srow & (RING - 1)) * ROWSTR + stLq;
        }
    };

    // A = staged rows committed at end of the CURRENT step (issued 1 step early)
    int sIA; uint32_t sVA[3];
    issue(yStart + RB + 1, sIA, sVA);

    const int colp = tid & (SLABW - 1);
    const int prow = tid >> 8;                // 0..3
    const int x = xbase + colp;
    // exact: x has <=10 mantissa bits; pow-2 scale and -1 are exact
    const float base_x = (float)x * (2.0f * INV_W) - 1.0f;

    __syncthreads();                          // prefill visible

    float acc = 0.0f;

#pragma unroll 1
    for (int ys = yStart; ys < yStart + SLABH; ys += RPS) {
        // ---- issue NEXT step's staged im1 rows (depth-2 prefetch) ----
        int sIB; uint32_t sVB[3];
        issue(ys + RB + 1 + RPS, sIB, sVB);

        // ---- compute this thread's pixel (ring reads rows ys-RA..ys+RB) ----
        const int y = ys + prow;
        const int zoff = y * W + x;
        const float2 f = *reinterpret_cast<const float2*>(flb + 2 * zoff);

        // bit-exact compressed index math (proof: round-8 note)
        const float base_y = (float)y * (2.0f * INV_H) - 1.0f;  // exact
        const float gx = __builtin_fmaf(f.x, INV_W, base_x);
        const float gy = __builtin_fmaf(f.y, INV_H, base_y);
        const float ixf = __builtin_fmaf(gx + 1.0f, 512.0f, -0.5f);
        const float iyf = __builtin_fmaf(gy + 1.0f, 256.0f, -0.5f);

        const float x0f = floorf(ixf), y0f = floorf(iyf);
        const float wx1 = ixf - x0f, wx0 = 1.0f - wx1;
        const float wy1 = iyf - y0f, wy0 = 1.0f - wy1;
        const int x0 = (int)x0f, y0 = (int)y0f;
        const int y1 = y0 + 1;
        const bool vx0 = (x0 >= 0) & (x0 < W);
        const bool vx1 = (x0 >= -1) & (x0 < W - 1);     // == valid(x1)
        const bool vy0 = (y0 >= 0) & (y0 < H);
        const bool vy1 = (y1 >= 0) & (y1 < H);
        // s0 = (x0c != xL) <=> x0 >= W-1 ; s1 = (x1c != xL) <=> x0 >= 0  (round-12 proof)
        const bool s0 = (x0 >= W - 1), s1 = (x0 >= 0);

        // weight-fold (round-13 proof, bit-exact in f32)
        const float px0 = wx0 * (float)vx0;
        const float px1 = wx1 * (float)vx1;
        const float u0 = (s0 ? 0.0f : px0) + (s1 ? 0.0f : px1);
        const float u1 = (s0 ? px0 : 0.0f) + (s1 ? px1 : 0.0f);
        const float mT = wy0 * (float)vy0;
        const float mB = wy1 * (float)vy1;
        const float aT0 = mT * u0, aT1 = mT * u1;
        const float aB0 = mB * u0, aB1 = mB * u1;

        const int xL  = min(max(x0, 0), W - 2);
        const int y0c = min(max(y0, 0), H - 1);
        const int y1c = min(max(y1, 0), H - 1);

        const int jj = xL - xbase + XH;
        const bool inR = (y0c >= ys - RA) & (y1c <= ys + RB) &
                         ((unsigned)jj <= (unsigned)(SWD - 2));

        const float z0 = im2b[zoff];
        const float z1 = im2b[HW + zoff];
        const float z2 = im2b[2 * HW + zoff];

        float wp0, wp1, wp2;
        if (inR) {
            const int q  = jj >> 1;
            const int sh = (jj & 1) << 4;
            const int aT = (y0c & (RING - 1)) * ROWSTR + (q << 2);
            const int aB = (y1c & (RING - 1)) * ROWSTR + (q << 2);
            // 2x ds_read_b128 per row: pair q {c0,c1,c2,pad} and pair q+1
            const uint4 Tq  = *reinterpret_cast<const uint4*>(sm32 + aT);
            const uint4 Tq1 = *reinterpret_cast<const uint4*>(sm32 + aT + QSTR);
            const uint4 Bq  = *reinterpret_cast<const uint4*>(sm32 + aB);
            const uint4 Bq1 = *reinterpret_cast<const uint4*>(sm32 + aB + QSTR);
            const float2 t0 = unpackh2(alignsel(Tq1.x, Tq.x, sh));
            const float2 b0 = unpackh2(alignsel(Bq1.x, Bq.x, sh));
            const float2 t1 = unpackh2(alignsel(Tq1.y, Tq.y, sh));
            const float2 b1 = unpackh2(alignsel(Bq1.y, Bq.y, sh));
            const float2 t2 = unpackh2(alignsel(Tq1.z, Tq.z, sh));
            const float2 b2 = unpackh2(alignsel(Bq1.z, Bq.z, sh));
            wp0 = ((aT0 * t0.x + aT1 * t0.y) + aB0 * b0.x) + aB1 * b0.y;
            wp1 = ((aT0 * t1.x + aT1 * t1.y) + aB0 * b1.x) + aB1 * b1.y;
            wp2 = ((aT0 * t2.x + aT1 * t2.y) + aB0 * b2.x) + aB1 * b2.y;
        } else {                              // rare (~0.2%/px): exact f32 global path
            const int oT = y0c * W + xL, oB = y1c * W + xL;
            const float2 ta = ld2g(im1b + oT),            ba = ld2g(im1b + oB);
            const float2 tb = ld2g(im1b + HW + oT),       bb = ld2g(im1b + HW + oB);
            const float2 tc = ld2g(im1b + 2 * HW + oT),   bc = ld2g(im1b + 2 * HW + oB);
            wp0 = ((aT0 * ta.x + aT1 * ta.y) + aB0 * ba.x) + aB1 * ba.y;
            wp1 = ((aT0 * tb.x + aT1 * tb.y) + aB0 * bb.x) + aB1 * bb.y;
            wp2 = ((aT0 * tc.x + aT1 * tc.y) + aB0 * bc.x) + aB1 * bc.y;
        }
        acc += fabsf(z0 - wp0) + fabsf(z1 - wp1) + fabsf(z2 - wp2);

        // ---- commit A: written slots (rows ys+17..ys+20 -> old ys-15..ys-12)
        // are disjoint from all rows read this step ([ys-11, ys+16]); one
        // barrier orders step->step (round-7 proof). ----
        if (sIA >= 0)
            *reinterpret_cast<uint4*>(sm32 + sIA) = make_uint4(sVA[0], sVA[1], sVA[2], 0u);
        __syncthreads();

        sIA = sIB; sVA[0] = sVB[0]; sVA[1] = sVB[1]; sVA[2] = sVB[2];
    }

    // ---------------- block reduction ----------------
#pragma unroll
    for (int o = 32; o > 0; o >>= 1)
        acc += __shfl_down(acc, o, 64);
    const int lane = tid & 63;
    const int wid  = tid >> 6;
    if (lane == 0) red[wid] = acc;
    __syncthreads();
    if (tid == 0) {
        float s = 0.0f;
#pragma unroll
        for (int wv = 0; wv < BLOCK / 64; ++wv) s += red[wv];
        partials[bid] = s;
    }
}

__global__ __launch_bounds__(256) void flow_loss_reduce(
    const float* __restrict__ partials, float* __restrict__ out)
{
    __shared__ double lds[256];
    double acc = 0.0;
    for (int i = threadIdx.x; i < GRID; i += 256) acc += (double)partials[i];
    lds[threadIdx.x] = acc;
    __syncthreads();
    for (int o = 128; o > 0; o >>= 1) {
        if (threadIdx.x < o) lds[threadIdx.x] += lds[threadIdx.x + o];
        __syncthreads();
    }
    if (threadIdx.x == 0) out[0] = (float)(lds[0] / (double)(W * H));
}

} // namespace

extern "C" void kernel_launch(void* const* d_in, const int* in_sizes, int n_in,
                              void* d_out, int out_size, void* d_ws, size_t ws_size,
                              hipStream_t stream) {
    const float* flow = (const float*)d_in[0];
    const float* im1  = (const float*)d_in[1];
    const float* im2  = (const float*)d_in[2];
    float* out = (float*)d_out;
    float* partials = (float*)d_ws;

    flow_loss_partial<<<GRID, BLOCK, 0, stream>>>(flow, im1, im2, partials);
    flow_loss_reduce<<<1, 256, 0, stream>>>(partials, out);
}

// Round 16
// 57.978 us; speedup vs baseline: 1.0761x; 1.0435x over previous
//
#include <hip/hip_runtime.h>
#include <hip/hip_fp16.h>

namespace {

constexpr int B = 16, C = 3, H = 512, W = 1024;
constexpr int HW = H * W;               // 2^19
constexpr int SLABW = 256, SLABH = 64;
constexpr int XH  = 16;                 // x halo
constexpr int SWD = SLABW + 2 * XH;     // 288 staged cols
constexpr int PAIRS = SWD / 2;          // 144 half2 pairs per row
constexpr int PADP = 147;               // pair stride; row bank-shift 19, gcd(19,32)=1
constexpr int RING = 32;                // ring rows (power of 2)
constexpr int RA = 11;                  // rows behind
constexpr int RB = 16;                  // rows ahead
constexpr int RPS = 4;                  // rows per step
constexpr int BLOCK = 1024;
constexpr int TX = W / SLABW;           // 4
constexpr int TY = H / SLABH;           // 8
constexpr int GRID = B * TX * TY;       // 512 blocks = 2/CU (32 waves = HW cap)
constexpr int PF_ROWS = RA + RB + 1;    // 28 prefill rows
constexpr int STG_P = C * RPS * PAIRS;  // 1728 staged pairs / step
constexpr int CHS = RING * PADP;        // 4704 dwords (18816 B/channel)

constexpr float INV_W = 1.0f / 1024.0f;
constexpr float INV_H = 1.0f / 512.0f;

// 4B-aligned float2 (adjacent-corner pair at arbitrary dword offset)
__device__ __forceinline__ float2 ld2g(const float* p) {
    struct __attribute__((packed, aligned(4))) F2 { float a, b; };
    const F2 v = *reinterpret_cast<const F2*>(p);
    return make_float2(v.a, v.b);
}

// RNE pack of two f32 into packed half2 dword
__device__ __forceinline__ uint32_t packh2(float a, float b) {
    return (uint32_t)__half_as_ushort(__float2half_rn(a))
         | ((uint32_t)__half_as_ushort(__float2half_rn(b)) << 16);
}
__device__ __forceinline__ float2 unpackh2(uint32_t u) {
    const __half2 h = __builtin_bit_cast(__half2, u);
    return make_float2(__low2float(h), __high2float(h));
}
// (hi:lo) >> sh, sh in {0,16} -> v_alignbit_b32
__device__ __forceinline__ uint32_t alignsel(uint32_t hi, uint32_t lo, int sh) {
    return (uint32_t)(((((uint64_t)hi) << 32) | (uint64_t)lo) >> sh);
}

__global__ __launch_bounds__(BLOCK, 8) void flow_loss_partial(
    const float* __restrict__ flow,   // (B,H,W,2)
    const float* __restrict__ im1,    // (B,C,H,W)
    const float* __restrict__ im2,    // (B,C,H,W)
    float* __restrict__ partials)     // [GRID]
{
    __shared__ uint32_t sm32[C * CHS];        // 56448 B -> 2 blocks/CU
    __shared__ float red[BLOCK / 64];

    const int tid = threadIdx.x;
    const int bid = blockIdx.x;
    const int b   = bid >> 5;                 // 32 slabs per image
    const int tt  = bid & 31;
    const int tyi = tt >> 2;                  // 8 y-slabs
    const int txi = tt & 3;                   // 4 x-slabs
    const int xbase  = txi * SLABW;
    const int yStart = tyi * SLABH;
    const int xb0    = xbase - XH;            // even

    const float* __restrict__ im1b = im1 + b * C * HW;
    const float* __restrict__ im2b = im2 + b * C * HW;
    const float* __restrict__ flb  = flow + 2 * (b * HW);

    // ---------------- prefill ring: rows yStart-RA .. yStart+RB ----------------
    for (int e = tid; e < PF_ROWS * C * PAIRS; e += BLOCK) {
        const int q  = e % PAIRS;
        const int rc = e / PAIRS;             // 0..83
        const int c  = rc / PF_ROWS;
        const int ri = rc - c * PF_ROWS;
        const int row = yStart - RA + ri;
        if (row >= 0) {                       // row <= yStart+RB < H always
            const int g0 = min(max(xb0 + 2 * q, 0), W - 1);
            const int g1 = min(max(xb0 + 2 * q + 1, 0), W - 1);
            const float a = im1b[c * HW + row * W + g0];
            const float d = im1b[c * HW + row * W + g1];
            sm32[c * CHS + (row & (RING - 1)) * PADP + q] = packh2(a, d);
        }
    }

    // ---- hoisted staging descriptors (tid-dependent only), pair granularity ----
    // k=0: e = tid always active. k=1: active iff tid < STG_P-1024 (=704).
    int  stSr[2], stG0[2], stG1[2], stL[2];
    const bool stOK1 = (tid < STG_P - BLOCK);
#pragma unroll
    for (int k = 0; k < 2; ++k) {
        const int e  = (k == 0) ? tid : (stOK1 ? BLOCK + tid : 0);
        const int q  = e % PAIRS;
        const int rc = e / PAIRS;             // 0..11
        const int c  = rc >> 2;
        stSr[k] = rc & 3;
        const int g0 = min(max(xb0 + 2 * q, 0), W - 1);
        const int g1 = min(max(xb0 + 2 * q + 1, 0), W - 1);
        stG0[k] = c * HW + g0;
        stG1[k] = c * HW + g1;
        stL[k]  = c * CHS + q;
    }

    // issue staged loads for rows r0..r0+RPS-1 into regs (no LDS touch)
    auto issue = [&](int r0, int (&sIdx)[2], uint32_t (&sVal)[2]) {
#pragma unroll
        for (int k = 0; k < 2; ++k) {
            const int srow = r0 + stSr[k];
            int idx = -1; uint32_t v = 0;
            const bool act = (k == 0 || stOK1) & (srow < H);
            if (act) {
                const float a = im1b[stG0[k] + (srow << 10)];
                const float d = im1b[stG1[k] + (srow << 10)];
                v   = packh2(a, d);
                idx = stL[k] + (srow & (RING - 1)) * PADP;
            }
            sIdx[k] = idx; sVal[k] = v;
        }
    };

    // A = staged rows committed at end of the CURRENT step (issued 1 step early)
    int sIA[2]; uint32_t sVA[2];
    issue(yStart + RB + 1, sIA, sVA);

    const int colp = tid & (SLABW - 1);
    const int prow = tid >> 8;                // 0..3
    const int x = xbase + colp;
    // exact: x has <=10 mantissa bits; pow-2 scale and -1 are exact
    const float base_x = (float)x * (2.0f * INV_W) - 1.0f;

    __syncthreads();                          // prefill visible

    float acc = 0.0f;

#pragma unroll 1
    for (int ys = yStart; ys < yStart + SLABH; ys += RPS) {
        // ---- issue NEXT step's staged im1 rows (depth-2 prefetch) ----
        int sIB[2]; uint32_t sVB[2];
        issue(ys + RB + 1 + RPS, sIB, sVB);

        // ---- issue ALL of this step's demand loads up front (intra-step order) ----
        const int y = ys + prow;
        const int zoff = y * W + x;
        const float2 f = *reinterpret_cast<const float2*>(flb + 2 * zoff);
        const float z0 = im2b[zoff];
        const float z1 = im2b[HW + zoff];
        const float z2 = im2b[2 * HW + zoff];

        // ---- geometry (ring reads rows ys-RA..ys+RB) ----
        // bit-exact compressed index math (proof: round-8 note)
        const float base_y = (float)y * (2.0f * INV_H) - 1.0f;  // exact
        const float gx = __builtin_fmaf(f.x, INV_W, base_x);
        const float gy = __builtin_fmaf(f.y, INV_H, base_y);
        const float ixf = __builtin_fmaf(gx + 1.0f, 512.0f, -0.5f);
        const float iyf = __builtin_fmaf(gy + 1.0f, 256.0f, -0.5f);

        const float x0f = floorf(ixf), y0f = floorf(iyf);
        const float wx1 = ixf - x0f, wx0 = 1.0f - wx1;
        const float wy1 = iyf - y0f, wy0 = 1.0f - wy1;
        const int x0 = (int)x0f, y0 = (int)y0f;
        const int y1 = y0 + 1;
        const bool vx0 = (x0 >= 0) & (x0 < W);
        const bool vx1 = (x0 >= -1) & (x0 < W - 1);     // == valid(x1)
        const bool vy0 = (y0 >= 0) & (y0 < H);
        const bool vy1 = (y1 >= 0) & (y1 < H);
        // s0 = (x0c != xL) <=> x0 >= W-1 ; s1 = (x1c != xL) <=> x0 >= 0  (round-12 proof)
        const bool s0 = (x0 >= W - 1), s1 = (x0 >= 0);

        // weight-fold (round-13 proof, bit-exact in f32)
        const float px0 = wx0 * (float)vx0;
        const float px1 = wx1 * (float)vx1;
        const float u0 = (s0 ? 0.0f : px0) + (s1 ? 0.0f : px1);
        const float u1 = (s0 ? px0 : 0.0f) + (s1 ? px1 : 0.0f);
        const float mT = wy0 * (float)vy0;
        const float mB = wy1 * (float)vy1;
        const float aT0 = mT * u0, aT1 = mT * u1;
        const float aB0 = mB * u0, aB1 = mB * u1;

        const int xL  = min(max(x0, 0), W - 2);
        const int y0c = min(max(y0, 0), H - 1);
        const int y1c = min(max(y1, 0), H - 1);

        const int jj = xL - xbase + XH;
        const bool inR = (y0c >= ys - RA) & (y1c <= ys + RB) &
                         ((unsigned)jj <= (unsigned)(SWD - 2));

        float wp0, wp1, wp2;
        __builtin_amdgcn_s_setprio(1);        // T5: 2 independent blocks/CU
        if (inR) {
            const int q  = jj >> 1;
            const int sh = (jj & 1) << 4;
            const int aT = (y0c & (RING - 1)) * PADP + q;
            const int aB = (y1c & (RING - 1)) * PADP + q;
            // per (row,channel): adjacent dword pair -> ds_read2_b32
            const uint32_t dT0a = sm32[aT],           dT0b = sm32[aT + 1];
            const uint32_t dB0a = sm32[aB],           dB0b = sm32[aB + 1];
            const uint32_t dT1a = sm32[aT + CHS],     dT1b = sm32[aT + CHS + 1];
            const uint32_t dB1a = sm32[aB + CHS],     dB1b = sm32[aB + CHS + 1];
            const uint32_t dT2a = sm32[aT + 2 * CHS], dT2b = sm32[aT + 2 * CHS + 1];
            const uint32_t dB2a = sm32[aB + 2 * CHS], dB2b = sm32[aB + 2 * CHS + 1];
            const float2 t0 = unpackh2(alignsel(dT0b, dT0a, sh));
            const float2 b0 = unpackh2(alignsel(dB0b, dB0a, sh));
            const float2 t1 = unpackh2(alignsel(dT1b, dT1a, sh));
            const float2 b1 = unpackh2(alignsel(dB1b, dB1a, sh));
            const float2 t2 = unpackh2(alignsel(dT2b, dT2a, sh));
            const float2 b2 = unpackh2(alignsel(dB2b, dB2a, sh));
            wp0 = ((aT0 * t0.x + aT1 * t0.y) + aB0 * b0.x) + aB1 * b0.y;
            wp1 = ((aT0 * t1.x + aT1 * t1.y) + aB0 * b1.x) + aB1 * b1.y;
            wp2 = ((aT0 * t2.x + aT1 * t2.y) + aB0 * b2.x) + aB1 * b2.y;
        } else {                              // rare (~0.2%/px): exact f32 global path
            const int oT = y0c * W + xL, oB = y1c * W + xL;
            const float2 ta = ld2g(im1b + oT),            ba = ld2g(im1b + oB);
            const float2 tb = ld2g(im1b + HW + oT),       bb = ld2g(im1b + HW + oB);
            const float2 tc = ld2g(im1b + 2 * HW + oT),   bc = ld2g(im1b + 2 * HW + oB);
            wp0 = ((aT0 * ta.x + aT1 * ta.y) + aB0 * ba.x) + aB1 * ba.y;
            wp1 = ((aT0 * tb.x + aT1 * tb.y) + aB0 * bb.x) + aB1 * bb.y;
            wp2 = ((aT0 * tc.x + aT1 * tc.y) + aB0 * bc.x) + aB1 * bc.y;
        }
        acc += fabsf(z0 - wp0) + fabsf(z1 - wp1) + fabsf(z2 - wp2);
        __builtin_amdgcn_s_setprio(0);

        // ---- commit A: written slots (rows ys+17..ys+20 -> old ys-15..ys-12)
        // are disjoint from all rows read this step ([ys-11, ys+16]); one
        // barrier orders step->step (round-7 proof). ----
#pragma unroll
        for (int k = 0; k < 2; ++k)
            if (sIA[k] >= 0) sm32[sIA[k]] = sVA[k];
        __syncthreads();

#pragma unroll
        for (int k = 0; k < 2; ++k) { sIA[k] = sIB[k]; sVA[k] = sVB[k]; }
    }

    // ---------------- block reduction ----------------
#pragma unroll
    for (int o = 32; o > 0; o >>= 1)
        acc += __shfl_down(acc, o, 64);
    const int lane = tid & 63;
    const int wid  = tid >> 6;
    if (lane == 0) red[wid] = acc;
    __syncthreads();
    if (tid == 0) {
        float s = 0.0f;
#pragma unroll
        for (int wv = 0; wv < BLOCK / 64; ++wv) s += red[wv];
        partials[bid] = s;
    }
}

__global__ __launch_bounds__(256) void flow_loss_reduce(
    const float* __restrict__ partials, float* __restrict__ out)
{
    __shared__ double lds[256];
    double acc = 0.0;
    for (int i = threadIdx.x; i < GRID; i += 256) acc += (double)partials[i];
    lds[threadIdx.x] = acc;
    __syncthreads();
    for (int o = 128; o > 0; o >>= 1) {
        if (threadIdx.x < o) lds[threadIdx.x] += lds[threadIdx.x + o];
        __syncthreads();
    }
    if (threadIdx.x == 0) out[0] = (float)(lds[0] / (double)(W * H));
}

} // namespace

extern "C" void kernel_launch(void* const* d_in, const int* in_sizes, int n_in,
                              void* d_out, int out_size, void* d_ws, size_t ws_size,
                              hipStream_t stream) {
    const float* flow = (const float*)d_in[0];
    const float* im1  = (const float*)d_in[1];
    const float* im2  = (const float*)d_in[2];
    float* out = (float*)d_out;
    float* partials = (float*)d_ws;

    flow_loss_partial<<<GRID, BLOCK, 0, stream>>>(flow, im1, im2, partials);
    flow_loss_reduce<<<1, 256, 0, stream>>>(partials, out);
}